// Round 8
// baseline (1210.370 us; speedup 1.0000x reference)
//
#include <hip/hip_runtime.h>

typedef _Float16 half_t;
typedef _Float16 half8 __attribute__((ext_vector_type(8)));
typedef float floatx4 __attribute__((ext_vector_type(4)));

#define NSEQ   256      // B*S
#define TLEN   128
#define EMBD   512
#define UNITSZ 512
#define GC     2048     // 4*UNITS
#define NTOK   32768    // NSEQ*TLEN
#define NCOL   4096     // 2 dirs * GC
#define KDIM   512

// workspace layout (bytes)
constexpr size_t OFF_EMB = 0;                    // emb_f16 32MB; first 2MB reused as tagged hbuf32 after gemm
constexpr size_t OFF_WT  = 33554432;             // WcatT fp16 [4096][512] = 4,194,304
constexpr size_t OFF_UT  = OFF_WT + 4194304;     // UcatT fp16 [4096][512] = 4,194,304
constexpr size_t OFF_HB  = OFF_UT + 4194304;     // (unused)
constexpr size_t OFF_CNT = OFF_HB + 1048576;     // (unused)
constexpr size_t OFF_MSK = OFF_CNT + 4096;       // mask bits: 256 * 2 u64 = 4096 B
constexpr size_t OFF_XW  = OFF_MSK + 4096;       // xW fp16 [32768][4096] = 268,435,456

__device__ inline float sigm(float x)  { return 1.0f / (1.0f + __expf(-x)); }
__device__ inline float tanhx(float x) { return 2.0f / (1.0f + __expf(-2.0f * x)) - 1.0f; }

// ---------------------------------------------------------------------------
// Tagged-h exchange v2 (R8). Protocol & layout PROVEN correct by R5 (passed,
// absmax 2.44e-4): hbuf32[dir][par][row 256][unit 512] dwords, each dword =
// (step_tag << 16) | h_fp16_bits. 4B aligned stores are atomic -> every dword
// is self-describing; producer is FIRE-AND-FORGET (no drain, no sync, no
// flag); the consumer's data load IS the poll (minscan tag check + retry).
// Parity double-buffer => tags per buffer strictly increase (ABA-safe).
// All exchange traffic agent-scope sc0 sc1 (R2: L2-scope leaks staleness on
// gfx950 — do not retry). R6 lesson: never keep more asm-output loads in
// flight than fit in registers (spilled in-flight output = garbage); max here
// is 16 dwordx4 (R5-proven liveness).
// R5->R8 schedule fixes: no tail vmcnt(0) (stores/prefetch drain lazily in
// the next probe, overlapping the producer wait); batch1 pinned before MFMA
// kk0-7 so its RT hides under compute; probe tight-spins first.
// ---------------------------------------------------------------------------
__device__ inline unsigned ld_probe(const unsigned* p) {
    unsigned v;
    asm volatile("global_load_dword %0, %1, off sc0 sc1\n\t"
                 "s_waitcnt vmcnt(0)" : "=v"(v) : "v"(p) : "memory");
    __builtin_amdgcn_sched_barrier(0);
    return v;
}

__device__ inline void st_tag(unsigned* p, unsigned v) {
    asm volatile("global_store_dword %0, %1, off sc0 sc1" :: "v"(p), "v"(v) : "memory");
}

// issue 16 dwordx4 tagged-h loads (8 kk slices), NO wait — caller fences.
__device__ inline void hb16(const unsigned* p, uint4* d) {
    asm volatile(
        "global_load_dwordx4 %0, %16, off sc0 sc1\n\t"
        "global_load_dwordx4 %1, %16, off offset:16 sc0 sc1\n\t"
        "global_load_dwordx4 %2, %16, off offset:128 sc0 sc1\n\t"
        "global_load_dwordx4 %3, %16, off offset:144 sc0 sc1\n\t"
        "global_load_dwordx4 %4, %16, off offset:256 sc0 sc1\n\t"
        "global_load_dwordx4 %5, %16, off offset:272 sc0 sc1\n\t"
        "global_load_dwordx4 %6, %16, off offset:384 sc0 sc1\n\t"
        "global_load_dwordx4 %7, %16, off offset:400 sc0 sc1\n\t"
        "global_load_dwordx4 %8, %16, off offset:512 sc0 sc1\n\t"
        "global_load_dwordx4 %9, %16, off offset:528 sc0 sc1\n\t"
        "global_load_dwordx4 %10, %16, off offset:640 sc0 sc1\n\t"
        "global_load_dwordx4 %11, %16, off offset:656 sc0 sc1\n\t"
        "global_load_dwordx4 %12, %16, off offset:768 sc0 sc1\n\t"
        "global_load_dwordx4 %13, %16, off offset:784 sc0 sc1\n\t"
        "global_load_dwordx4 %14, %16, off offset:896 sc0 sc1\n\t"
        "global_load_dwordx4 %15, %16, off offset:912 sc0 sc1"
        : "=&v"(d[0]), "=&v"(d[1]), "=&v"(d[2]), "=&v"(d[3]),
          "=&v"(d[4]), "=&v"(d[5]), "=&v"(d[6]), "=&v"(d[7]),
          "=&v"(d[8]), "=&v"(d[9]), "=&v"(d[10]), "=&v"(d[11]),
          "=&v"(d[12]), "=&v"(d[13]), "=&v"(d[14]), "=&v"(d[15])
        : "v"(p) : "memory");
}

__device__ inline unsigned minscan16(const uint4* d) {
    unsigned m = 0xffffffffu;
#pragma unroll
    for (int i = 0; i < 16; ++i) {
        m = m < d[i].x ? m : d[i].x;
        m = m < d[i].y ? m : d[i].y;
        m = m < d[i].z ? m : d[i].z;
        m = m < d[i].w ? m : d[i].w;
    }
    return m;
}

__device__ inline int fresh16(const uint4* d, unsigned tg) {
    return __all((int)((minscan16(d) >> 16) == tg));
}

__device__ inline half8 unpack8(const uint4& a, const uint4& b) {
    union { unsigned u[4]; half8 v; } c;
    c.u[0] = (a.x & 0xffffu) | (a.y << 16);
    c.u[1] = (a.z & 0xffffu) | (a.w << 16);
    c.u[2] = (b.x & 0xffffu) | (b.y << 16);
    c.u[3] = (b.z & 0xffffu) | (b.w << 16);
    return c.v;
}

// issue next-step xW prefetch (16 x 2B, immutable, plain cached loads), NO
// wait — lazily drained by the next probe's vmcnt(0), which overlaps the
// producer-straggler wait (R4/R5 lesson: never drain it on the signal or
// observe critical path).
__device__ inline void xv_issue(const half_t* p0, const half_t* p1,
                                const half_t* p2, const half_t* p3,
                                unsigned* xvr) {
    asm volatile(
        "global_load_ushort %0, %16, off\n\t"
        "global_load_ushort %1, %16, off offset:1024\n\t"
        "global_load_ushort %2, %16, off offset:2048\n\t"
        "global_load_ushort %3, %16, off offset:3072\n\t"
        "global_load_ushort %4, %17, off\n\t"
        "global_load_ushort %5, %17, off offset:1024\n\t"
        "global_load_ushort %6, %17, off offset:2048\n\t"
        "global_load_ushort %7, %17, off offset:3072\n\t"
        "global_load_ushort %8, %18, off\n\t"
        "global_load_ushort %9, %18, off offset:1024\n\t"
        "global_load_ushort %10, %18, off offset:2048\n\t"
        "global_load_ushort %11, %18, off offset:3072\n\t"
        "global_load_ushort %12, %19, off\n\t"
        "global_load_ushort %13, %19, off offset:1024\n\t"
        "global_load_ushort %14, %19, off offset:2048\n\t"
        "global_load_ushort %15, %19, off offset:3072"
        : "=&v"(xvr[0]), "=&v"(xvr[1]), "=&v"(xvr[2]), "=&v"(xvr[3]),
          "=&v"(xvr[4]), "=&v"(xvr[5]), "=&v"(xvr[6]), "=&v"(xvr[7]),
          "=&v"(xvr[8]), "=&v"(xvr[9]), "=&v"(xvr[10]), "=&v"(xvr[11]),
          "=&v"(xvr[12]), "=&v"(xvr[13]), "=&v"(xvr[14]), "=&v"(xvr[15])
        : "v"(p0), "v"(p1), "v"(p2), "v"(p3) : "memory");
}

// ---------------- pack W/U (fp32 [512][2048] per dir) -> transposed fp16 [dir*2048+gcol][512]
__global__ void pack_kernel(const float* __restrict__ Wf, const float* __restrict__ Uf,
                            const float* __restrict__ Wb, const float* __restrict__ Ub,
                            half_t* __restrict__ WT, half_t* __restrict__ UT) {
    int c = blockIdx.x * 256 + threadIdx.x;          // 524288 chunks total
    int arr = c >> 18;                               // 0 = W, 1 = U
    int r = c & 262143;                              // 262144 = 4096*64
    int kc = r >> 12;                                // 64 chunks of 8 k
    int gc = r & 4095;                               // lanes vary gc -> coalesced reads
    int dir = gc >> 11;
    int g = gc & 2047;
    const float* src = (arr == 0) ? (dir ? Wb : Wf) : (dir ? Ub : Uf);
    half_t* dst = (arr == 0) ? WT : UT;
    half8 v;
#pragma unroll
    for (int j = 0; j < 8; ++j)
        v[j] = (half_t)src[(size_t)(kc * 8 + j) * GC + g];
    *(half8*)(dst + (size_t)gc * KDIM + kc * 8) = v;
}

// ---------------- zero tagged hbuf32 (runs AFTER gemm; aliases dead embf;
// end-of-dispatch flush publishes — proven by R5 passing)
__global__ void zero32_kernel(unsigned* __restrict__ p) {
    p[blockIdx.x * 256 + threadIdx.x] = 0u;          // 524288 dwords = 2MB
}

// ---------------- pack per-row validity masks: mk[n] = 128 bits of (x!=0)
__global__ void mask_kernel(const int* __restrict__ x, unsigned long long* __restrict__ mk) {
    int n = blockIdx.x;       // 256 blocks x 64 threads
    int l = threadIdx.x;
    unsigned long long b0 = __ballot(x[n * TLEN + l] != 0);
    unsigned long long b1 = __ballot(x[n * TLEN + 64 + l] != 0);
    if (l == 0) { mk[n * 2] = b0; mk[n * 2 + 1] = b1; }
}

// ---------------- gather: emb_f16[token][512] = fp16(emb_table[x[token]][:])
__global__ void gather_kernel(const int* __restrict__ x, const float* __restrict__ tab,
                              half_t* __restrict__ embf) {
    int g = blockIdx.x * 256 + threadIdx.x;          // 2,097,152 chunks of 8
    int token = g >> 6;
    int k = (g & 63) * 8;
    int id = x[token];
    const float* s = tab + (size_t)id * EMBD + k;
    float4 a = *(const float4*)(s);
    float4 b = *(const float4*)(s + 4);
    half8 v;
    v[0] = (half_t)a.x; v[1] = (half_t)a.y; v[2] = (half_t)a.z; v[3] = (half_t)a.w;
    v[4] = (half_t)b.x; v[5] = (half_t)b.y; v[6] = (half_t)b.z; v[7] = (half_t)b.w;
    *(half8*)(embf + (size_t)token * EMBD + k) = v;
}

// ---------------- GEMM: xW[32768][4096] = emb_f16 @ WcatT^T + bias, fp16 out
__global__ __launch_bounds__(256, 2) void gemm_kernel(const half_t* __restrict__ embf,
                                                      const half_t* __restrict__ WT,
                                                      const float* __restrict__ bf,
                                                      const float* __restrict__ bb,
                                                      half_t* __restrict__ xw) {
    __shared__ half_t As[128 * 40];   // [row][32+8pad]
    __shared__ half_t Bs[128 * 40];   // B^T tile: [col][32+8pad]
    int bx = blockIdx.x;
    int bm = bx & 255, bn = bx >> 8;
    int r0 = bm * 128, c0 = bn * 128;
    int tid = threadIdx.x;
    int w = tid >> 6, l = tid & 63;
    int q = l >> 4, cl = l & 15;
    int mq = (w >> 1) * 64, nq = (w & 1) * 64;

    floatx4 acc[4][4];
#pragma unroll
    for (int a = 0; a < 4; ++a)
#pragma unroll
        for (int b = 0; b < 4; ++b) acc[a][b] = (floatx4){0.f, 0.f, 0.f, 0.f};

    for (int kb = 0; kb < 16; ++kb) {
#pragma unroll
        for (int cc = 0; cc < 2; ++cc) {
            int c = tid + cc * 256;
            int row = c >> 2, qt = c & 3;
            half8 va = *(const half8*)(embf + (size_t)(r0 + row) * KDIM + kb * 32 + qt * 8);
            *(half8*)(As + row * 40 + qt * 8) = va;
            half8 vb = *(const half8*)(WT + (size_t)(c0 + row) * KDIM + kb * 32 + qt * 8);
            *(half8*)(Bs + row * 40 + qt * 8) = vb;
        }
        __syncthreads();
        half8 af[4], bfr[4];
#pragma unroll
        for (int mb = 0; mb < 4; ++mb)
            af[mb] = *(const half8*)(As + (mq + mb * 16 + cl) * 40 + q * 8);
#pragma unroll
        for (int nb = 0; nb < 4; ++nb)
            bfr[nb] = *(const half8*)(Bs + (nq + nb * 16 + cl) * 40 + q * 8);
#pragma unroll
        for (int mb = 0; mb < 4; ++mb)
#pragma unroll
            for (int nb = 0; nb < 4; ++nb)
                acc[mb][nb] = __builtin_amdgcn_mfma_f32_16x16x32_f16(af[mb], bfr[nb], acc[mb][nb], 0, 0, 0);
        __syncthreads();
    }
    // epilogue: + bias, store fp16
#pragma unroll
    for (int nb = 0; nb < 4; ++nb) {
        int col = c0 + nq + nb * 16 + cl;
        int dir = col >> 11, gcol = col & 2047;
        float bias = dir ? bb[gcol] : bf[gcol];
#pragma unroll
        for (int mb = 0; mb < 4; ++mb) {
#pragma unroll
            for (int r = 0; r < 4; ++r) {
                int row = r0 + mq + mb * 16 + q * 4 + r;
                xw[(size_t)row * NCOL + col] = (half_t)(acc[mb][nb][r] + bias);
            }
        }
    }
}

// ---------------------------------------------------------------------------
// Persistent bidirectional LSTM, 256 blocks x 256 threads, tagged-h v2:
//   per step (t>0): probe spin (tight first, 4B/lane over all 32 producer
//   waves x 2 row-halves; its vmcnt(0) lazily drains last step's stores +
//   prefetch DURING the wait) -> batch0 (16 dwordx4) + minscan check ->
//   unpack kk0-7 -> batch1 issue (pinned early; RT hides under MFMA) ->
//   acc init -> MFMA kk0-7 -> vmcnt(0) check batch1 -> MFMA kk8-15 ->
//   gates -> 4 tagged dword stores (fire-and-forget: the store IS the
//   signal) -> xW prefetch. No LDS, no barriers, no atomics, no flags, no
//   producer drain. All spins capped (fail measurably, never hang).
// ---------------------------------------------------------------------------
__global__ __launch_bounds__(256, 1) void lstm_kernel(const half_t* __restrict__ xw,
                                                      const half_t* __restrict__ UT,
                                                      unsigned* __restrict__ hb,
                                                      const unsigned long long* __restrict__ mk,
                                                      float* __restrict__ out) {
    int bx = blockIdx.x;
    int grp = bx & 31;              // group id (dir*16+rowg); members: bx = grp + 32*j
    int wgc = bx >> 5;              // member 0..7 = unit-column group
    int dir = grp >> 4;
    int rowg = grp & 15;
    int tid = threadIdx.x;
    int w = tid >> 6, l = tid & 63;
    int q = l >> 4, cl = l & 15;
    int cg = wgc * 4 + w;           // col-group 0..31
    int ub = cg * 16;               // unit base (per wave)
    int r0 = rowg * 16;             // sequence-row base

    // preload U B-frags: bfrag[kk*4+cf], cf = gate (immutable, cached)
    half8 bfrag[64];
#pragma unroll
    for (int kk = 0; kk < 16; ++kk)
#pragma unroll
        for (int cf = 0; cf < 4; ++cf)
            bfrag[kk * 4 + cf] = *(const half8*)(UT + (size_t)(dir * 2048 + cf * 512 + ub + cl) * KDIM + kk * 32 + q * 8);

    // preload this thread's 4 rows' validity masks (128 bits each)
    unsigned long long mlo[4], mhi[4];
#pragma unroll
    for (int r = 0; r < 4; ++r) {
        int n = r0 + q * 4 + r;
        mlo[r] = mk[n * 2];
        mhi[r] = mk[n * 2 + 1];
    }

    float cs[4] = {0.f, 0.f, 0.f, 0.f};
    float hs[4] = {0.f, 0.f, 0.f, 0.f};
    int colb = dir * 2048 + ub + cl;

    // tagged hbuf pointers (dword layout [dir][par][row][unit])
    unsigned* hbd = hb + (size_t)(dir * 2) * NSEQ * UNITSZ;
    const unsigned* ap0 = hbd + (size_t)(r0 + cl) * UNITSZ + q * 8;          // par0 read base
    const unsigned* ap1 = ap0 + (size_t)NSEQ * UNITSZ;
    unsigned* hw0 = hbd + (size_t)(r0 + q * 4) * UNITSZ + ub + cl;           // par0 write base
    unsigned* hw1 = hw0 + (size_t)NSEQ * UNITSZ;
    // probe: lane l covers producer block jb, wave wwp, row-half rr
    int jb = l & 7, wwp = (l >> 3) & 3, rr = (l >> 5) * 8;
    const unsigned* pp0 = hbd + (size_t)(r0 + rr) * UNITSZ + jb * 64 + wwp * 16;
    const unsigned* pp1 = pp0 + (size_t)NSEQ * UNITSZ;

    // xW row bases for prefetch
    const half_t* xb0 = xw + (size_t)(r0 + q * 4 + 0) * TLEN * NCOL + colb;
    const half_t* xb1 = xw + (size_t)(r0 + q * 4 + 1) * TLEN * NCOL + colb;
    const half_t* xb2 = xw + (size_t)(r0 + q * 4 + 2) * TLEN * NCOL + colb;
    const half_t* xb3 = xw + (size_t)(r0 + q * 4 + 3) * TLEN * NCOL + colb;

    // prefetch xW for t=0 (bias already baked in)
    unsigned xvr[16];
    {
        int tI = dir ? 127 : 0;
        xv_issue(xb0 + (size_t)tI * NCOL, xb1 + (size_t)tI * NCOL,
                 xb2 + (size_t)tI * NCOL, xb3 + (size_t)tI * NCOL, xvr);
    }
    asm volatile("s_waitcnt vmcnt(0)" ::: "memory");
    __builtin_amdgcn_sched_barrier(0);

#pragma unroll 1
    for (int t = 0; t < TLEN; ++t) {
        int tIdx = dir ? (127 - t) : t;
        int rpar = t & 1;
        floatx4 a0, a1, a2, a3;
        if (t > 0) {
            unsigned tg = (unsigned)t;
            // ---- probe spin (tight first; vmcnt(0) also drains our stores
            //      and the xW prefetch WHILE we wait for producers)
            const unsigned* pp = rpar ? pp1 : pp0;
            for (unsigned sp = 0;; ++sp) {
                unsigned pv = ld_probe(pp);
                if (__all((int)((pv >> 16) == tg))) break;
                if (sp >= (1u << 20)) break;            // hang-safety
                if (sp >= 8u) __builtin_amdgcn_s_sleep(1);
            }
            const unsigned* bp = rpar ? ap1 : ap0;
            // ---- batch0 (kk 0-7): load + full tag check (rare retry)
            uint4 d0[16];
            for (unsigned sp = 0;; ++sp) {
                hb16(bp, d0);
                asm volatile("s_waitcnt vmcnt(0)" ::: "memory");
                __builtin_amdgcn_sched_barrier(0);
                if (fresh16(d0, tg)) break;
                if (sp >= 65536u) break;                // hang-safety
            }
            half8 af[16];
#pragma unroll
            for (int kk = 0; kk < 8; ++kk)
                af[kk] = unpack8(d0[2 * kk], d0[2 * kk + 1]);
            // ---- issue batch1 NOW (pinned): RT hides under MFMA kk0-7
            uint4 d1[16];
            hb16(bp + 256, d1);
            __builtin_amdgcn_sched_barrier(0);
            // acc init from prefetched xW (drained by the probe's vmcnt(0))
#pragma unroll
            for (int r = 0; r < 4; ++r) {
                a0[r] = (float)__builtin_bit_cast(half_t, (unsigned short)xvr[r * 4 + 0]);
                a1[r] = (float)__builtin_bit_cast(half_t, (unsigned short)xvr[r * 4 + 1]);
                a2[r] = (float)__builtin_bit_cast(half_t, (unsigned short)xvr[r * 4 + 2]);
                a3[r] = (float)__builtin_bit_cast(half_t, (unsigned short)xvr[r * 4 + 3]);
            }
#pragma unroll
            for (int kk = 0; kk < 8; ++kk) {
                a0 = __builtin_amdgcn_mfma_f32_16x16x32_f16(af[kk], bfrag[kk * 4 + 0], a0, 0, 0, 0);
                a1 = __builtin_amdgcn_mfma_f32_16x16x32_f16(af[kk], bfrag[kk * 4 + 1], a1, 0, 0, 0);
                a2 = __builtin_amdgcn_mfma_f32_16x16x32_f16(af[kk], bfrag[kk * 4 + 2], a2, 0, 0, 0);
                a3 = __builtin_amdgcn_mfma_f32_16x16x32_f16(af[kk], bfrag[kk * 4 + 3], a3, 0, 0, 0);
            }
            asm volatile("s_waitcnt vmcnt(0)" ::: "memory");    // batch1 landed
            __builtin_amdgcn_sched_barrier(0);
            if (!fresh16(d1, tg)) {
                for (unsigned sp = 0;; ++sp) {
                    hb16(bp + 256, d1);
                    asm volatile("s_waitcnt vmcnt(0)" ::: "memory");
                    __builtin_amdgcn_sched_barrier(0);
                    if (fresh16(d1, tg)) break;
                    if (sp >= 65536u) break;            // hang-safety
                }
            }
#pragma unroll
            for (int kk = 8; kk < 16; ++kk)
                af[kk] = unpack8(d1[2 * (kk - 8)], d1[2 * (kk - 8) + 1]);
#pragma unroll
            for (int kk = 8; kk < 16; ++kk) {
                a0 = __builtin_amdgcn_mfma_f32_16x16x32_f16(af[kk], bfrag[kk * 4 + 0], a0, 0, 0, 0);
                a1 = __builtin_amdgcn_mfma_f32_16x16x32_f16(af[kk], bfrag[kk * 4 + 1], a1, 0, 0, 0);
                a2 = __builtin_amdgcn_mfma_f32_16x16x32_f16(af[kk], bfrag[kk * 4 + 2], a2, 0, 0, 0);
                a3 = __builtin_amdgcn_mfma_f32_16x16x32_f16(af[kk], bfrag[kk * 4 + 3], a3, 0, 0, 0);
            }
        } else {
            // t=0: z = xW only (h = 0)
#pragma unroll
            for (int r = 0; r < 4; ++r) {
                a0[r] = (float)__builtin_bit_cast(half_t, (unsigned short)xvr[r * 4 + 0]);
                a1[r] = (float)__builtin_bit_cast(half_t, (unsigned short)xvr[r * 4 + 1]);
                a2[r] = (float)__builtin_bit_cast(half_t, (unsigned short)xvr[r * 4 + 2]);
                a3[r] = (float)__builtin_bit_cast(half_t, (unsigned short)xvr[r * 4 + 3]);
            }
        }
        // gates + masked state update; tagged dword store = the signal
        unsigned* hdst = rpar ? hw0 : hw1;
        unsigned tagv = ((unsigned)(t + 1)) << 16;
#pragma unroll
        for (int r = 0; r < 4; ++r) {
            unsigned long long mw = (tIdx & 64) ? mhi[r] : mlo[r];
            bool keep = (mw >> (tIdx & 63)) & 1ull;
            float iv = sigm(a0[r]);
            float fv = sigm(a1[r]);
            float gv = tanhx(a2[r]);
            float ov = sigm(a3[r]);
            float cn = fv * cs[r] + iv * gv;
            float hn = ov * tanhx(cn);
            if (keep) { cs[r] = cn; hs[r] = hn; }
            unsigned hv = tagv | (unsigned)__builtin_bit_cast(unsigned short, (half_t)hs[r]);
            st_tag(hdst + r * 512, hv);
        }
        // next-step xW prefetch; NO tail drain (lazy-drained during the next
        // probe's wait — keeps the producer path pure fire-and-forget).
        if (t + 1 < TLEN) {
            int tN = dir ? (126 - t) : (t + 1);
            xv_issue(xb0 + (size_t)tN * NCOL, xb1 + (size_t)tN * NCOL,
                     xb2 + (size_t)tN * NCOL, xb3 + (size_t)tN * NCOL, xvr);
        }
    }
    // final output: out[n][dir*512 + unit]
#pragma unroll
    for (int r = 0; r < 4; ++r) {
        int n = r0 + q * 4 + r;
        out[(size_t)n * 1024 + dir * 512 + ub + cl] = hs[r];
    }
}

extern "C" void kernel_launch(void* const* d_in, const int* in_sizes, int n_in,
                              void* d_out, int out_size, void* d_ws, size_t ws_size,
                              hipStream_t stream) {
    const int*   x    = (const int*)d_in[0];
    const float* tab  = (const float*)d_in[1];
    const float* Wf   = (const float*)d_in[2];
    const float* Uf   = (const float*)d_in[3];
    const float* bf   = (const float*)d_in[4];
    const float* Wb   = (const float*)d_in[5];
    const float* Ub   = (const float*)d_in[6];
    const float* bb   = (const float*)d_in[7];
    float* out = (float*)d_out;

    char* ws = (char*)d_ws;
    half_t*   embf = (half_t*)(ws + OFF_EMB);
    half_t*   WT   = (half_t*)(ws + OFF_WT);
    half_t*   UT   = (half_t*)(ws + OFF_UT);
    unsigned* hb32 = (unsigned*)(ws + OFF_EMB);  // tagged hbuf reuses dead emb region
    unsigned long long* mkb = (unsigned long long*)(ws + OFF_MSK);
    half_t*   xw   = (half_t*)(ws + OFF_XW);

    pack_kernel<<<2048, 256, 0, stream>>>(Wf, Uf, Wb, Ub, WT, UT);
    mask_kernel<<<256, 64, 0, stream>>>(x, mkb);
    gather_kernel<<<8192, 256, 0, stream>>>(x, tab, embf);
    gemm_kernel<<<8192, 256, 0, stream>>>(embf, WT, bf, bb, xw);
    zero32_kernel<<<2048, 256, 0, stream>>>(hb32);
    lstm_kernel<<<256, 256, 0, stream>>>(xw, UT, hb32, mkb, out);
}